// Round 4
// baseline (552.141 us; speedup 1.0000x reference)
//
#include <hip/hip_runtime.h>
#include <hip/hip_bf16.h>

#define NROWS 131072
#define DIN   768
#define DD    512
#define KK    256

#define BM    64
#define BK    32
#define NSTEP 24            // DIN/BK
#define MARGIN_TH 1e-3f

typedef __attribute__((ext_vector_type(8))) short  short8;
typedef __attribute__((ext_vector_type(8))) unsigned short ushort8;
typedef __attribute__((ext_vector_type(4))) float  f32x4;

#define ASM_VMCNT10() asm volatile("s_waitcnt vmcnt(10)" ::: "memory")
#define ASM_LGKM0()   asm volatile("s_waitcnt lgkmcnt(0)" ::: "memory")
#define SCHED_BAR()   __builtin_amdgcn_sched_barrier(0)
#define BARRIER()     __builtin_amdgcn_s_barrier()

__device__ __forceinline__ unsigned short f2bf_rn(float x) {
    unsigned int u = __float_as_uint(x);
    unsigned int r = (u + 0x7fffu + ((u >> 16) & 1u)) >> 16;   // RNE
    return (unsigned short)r;
}
__device__ __forceinline__ float bf2f(unsigned short h) {
    return __uint_as_float(((unsigned int)h) << 16);
}

__device__ __forceinline__ void gl_lds16(const unsigned short* g, unsigned short* l) {
    __builtin_amdgcn_global_load_lds(
        (const __attribute__((address_space(1))) unsigned int*)g,
        (__attribute__((address_space(3))) unsigned int*)l, 16, 0, 0);
}

__device__ __forceinline__ void cvt_store(float4 a, float4 b,
                                          unsigned short* hd, unsigned short* ldst) {
    ushort8 hv, lv;
#pragma unroll
    for (int j = 0; j < 4; ++j) {
        unsigned short h = f2bf_rn(a[j]);
        hv[j] = h; lv[j] = f2bf_rn(a[j] - bf2f(h));
    }
#pragma unroll
    for (int j = 0; j < 4; ++j) {
        unsigned short h = f2bf_rn(b[j]);
        hv[j + 4] = h; lv[j + 4] = f2bf_rn(b[j] - bf2f(h));
    }
    *(ushort8*)hd = hv;
    *(ushort8*)ldst = lv;
}

// ---------------- w2: W2 = -2*enc_w@cb0^T -> bf16 hi/lo in bulk-LDS tile order; c2 ------
// grid 768 (one block per din row), 256 thr. Wave w handles cols [w*64, w*64+64).
// Coalesced: lane reads cb0[col][lane + 64*i]; fp64 shuffle-reduce.
// Wp layout: Wp[((size_t)s*2048 + u)*8 + j], u = lg*256+col (H) / 1024+lg*256+col (L),
//            din = s*32 + lg*8 + j.
__global__ __launch_bounds__(256) void w2_kernel(const float* __restrict__ enc_w,
                                                 const float* __restrict__ enc_b,
                                                 const float* __restrict__ cb,
                                                 unsigned short* __restrict__ Wp,
                                                 float* __restrict__ c2,
                                                 int* __restrict__ counter) {
    int jrow = blockIdx.x;               // din 0..767
    int t = threadIdx.x;
    int lane = t & 63, wv = t >> 6;
    __shared__ float wrow[DD];
    for (int d = t; d < DD; d += 256) wrow[d] = enc_w[(size_t)jrow * DD + d];
    __syncthreads();

    int s  = jrow >> 5;
    int kin = jrow & 31;
    int lg = kin >> 3;
    int jj = kin & 7;
    size_t baseH = ((size_t)s * 2048 + (size_t)lg * 256) * 8 + jj;

    for (int c = 0; c < 64; ++c) {
        int col = wv * 64 + c;
        const float* C = cb + (size_t)col * DD;
        double p = 0.0;
#pragma unroll
        for (int i = 0; i < 8; ++i) {
            int d = lane + 64 * i;
            p += (double)wrow[d] * (double)C[d];
        }
#pragma unroll
        for (int off = 1; off < 64; off <<= 1) p += __shfl_xor(p, off);
        if (lane == 0) {
            float w = (float)(-2.0 * p);
            unsigned short h = f2bf_rn(w);
            unsigned short l = f2bf_rn(w - bf2f(h));
            Wp[baseH + (size_t)col * 8]        = h;
            Wp[baseH + 8192 + (size_t)col * 8] = l;
        }
    }

    if (jrow == 0) {
        __syncthreads();
        for (int d = t; d < DD; d += 256) wrow[d] = enc_b[d];
        __syncthreads();
        for (int c = 0; c < 64; ++c) {
            int col = wv * 64 + c;
            const float* C = cb + (size_t)col * DD;
            double db = 0.0, nn = 0.0;
#pragma unroll
            for (int i = 0; i < 8; ++i) {
                int d = lane + 64 * i;
                double cv = C[d];
                db += (double)wrow[d] * cv;
                nn += cv * cv;
            }
#pragma unroll
            for (int off = 1; off < 64; off <<= 1) {
                db += __shfl_xor(db, off);
                nn += __shfl_xor(nn, off);
            }
            if (lane == 0) c2[col] = (float)(-2.0 * db + nn);
        }
        if (t == 0) *counter = 0;
    }
}

// ---------------- chain: per k walk 3-layer argmin chain (fp64, coalesced) + decoder ----
// grid 256 (one block per k), 256 thr. Wave w scores j in [w*64, w*64+64).
__global__ __launch_bounds__(256) void chain_kernel(const float* __restrict__ cb,
                                                    const float* __restrict__ dec_w,
                                                    const float* __restrict__ dec_b,
                                                    float* __restrict__ Tdec) {
    int k = blockIdx.x;
    int t = threadIdx.x;
    int lane = t & 63, wv = t >> 6;
    __shared__ float  q[DD];
    __shared__ double Tsum[DD];
    __shared__ double wbest[4];
    __shared__ int    wbesti[4];
    __shared__ int    sel;

    for (int d = t; d < DD; d += 256) {
        float v = cb[(size_t)k * DD + d];
        q[d] = v; Tsum[d] = (double)v;
    }

    for (int l = 1; l < 4; ++l) {
        __syncthreads();
        const float* C = cb + (size_t)l * KK * DD;
        double best = 1e300; int bi = 0;
        for (int c = 0; c < 64; ++c) {
            int j = wv * 64 + c;
            const float* Cj = C + (size_t)j * DD;
            double p = 0.0, nn = 0.0;
#pragma unroll
            for (int i = 0; i < 8; ++i) {
                int d = lane + 64 * i;
                double cv = Cj[d];
                p += (double)q[d] * cv;
                nn += cv * cv;
            }
            double sc = -2.0 * p + nn;
#pragma unroll
            for (int off = 1; off < 64; off <<= 1) sc += __shfl_xor(sc, off);
            if (sc < best) { best = sc; bi = j; }       // j ascending -> first-min
        }
        if (lane == 0) { wbest[wv] = best; wbesti[wv] = bi; }
        __syncthreads();
        if (t == 0) {
            double bv = wbest[0]; int bidx = wbesti[0];
            for (int g = 1; g < 4; ++g)
                if (wbest[g] < bv || (wbest[g] == bv && wbesti[g] < bidx)) { bv = wbest[g]; bidx = wbesti[g]; }
            sel = bidx;
        }
        __syncthreads();
        int i2 = sel;
        for (int d = t; d < DD; d += 256) {
            float v = C[(size_t)i2 * DD + d];
            q[d] = v; Tsum[d] += (double)v;
        }
    }
    __syncthreads();
    for (int n = t; n < DD; n += 256) {
        double a0 = 0, a1 = 0, a2 = 0, a3 = 0;
        for (int d = 0; d < DD; d += 4) {
            a0 += Tsum[d]     * (double)dec_w[(size_t)(d)     * DD + n];
            a1 += Tsum[d + 1] * (double)dec_w[(size_t)(d + 1) * DD + n];
            a2 += Tsum[d + 2] * (double)dec_w[(size_t)(d + 2) * DD + n];
            a3 += Tsum[d + 3] * (double)dec_w[(size_t)(d + 3) * DD + n];
        }
        Tdec[(size_t)k * DD + n] = (float)((double)dec_b[n] + a0 + a1 + a2 + a3);
    }
}

// ---------------- bulk: 2-deep counted-vmcnt MFMA pipeline ------------------------------
// grid 2048, block 256 (4 waves). Block tile 64 rows x 256 cols; wave tile 64x64 (cg=wv).
// LDS: X single-buf (h 4KB + l 4KB), W dbuf 2x32KB (H units 0..1023, L 1024..2047).
__global__ __launch_bounds__(256, 2) void bulk_kernel(const float* __restrict__ X,
                                                      const unsigned short* __restrict__ Wp,
                                                      const float* __restrict__ c2,
                                                      const float* __restrict__ Tdec,
                                                      float* __restrict__ out,
                                                      int* __restrict__ counter,
                                                      int* __restrict__ list) {
    __shared__ __align__(16) unsigned char smem[73728];
    unsigned short* Xh  = (unsigned short*)smem;              // 4KB
    unsigned short* Xl  = (unsigned short*)(smem + 4096);     // 4KB
    unsigned short* Wb0 = (unsigned short*)(smem + 8192);     // 32KB
    unsigned short* Wb1 = (unsigned short*)(smem + 40960);    // 32KB

    const int t    = threadIdx.x;
    const int lane = t & 63;
    const int wv   = t >> 6;        // col-group 0..3
    const int lr   = lane & 15;
    const int lg   = lane >> 4;
    const int row0 = blockIdx.x * BM;

    f32x4 acc[4][4];
#pragma unroll
    for (int rf = 0; rf < 4; ++rf)
#pragma unroll
        for (int cf = 0; cf < 4; ++cf) acc[rf][cf] = (f32x4){0.f, 0.f, 0.f, 0.f};

    // X staging addresses (loop-invariant): thread t loads x[row=t>>2][(t&3)*8 .. +8]
    const int xrow = t >> 2, xsub = t & 3;
    const float* xp_base = X + (size_t)(row0 + xrow) * DIN + xsub * 8;
    const int xu = (xsub * 64 + xrow) ^ (xsub << 1);          // swizzled unit
    unsigned short* xh_dst = Xh + xu * 8;
    unsigned short* xl_dst = Xl + xu * 8;

    float4 xa0, xb0, xa1, xb1;

    // ---- prologue: clump 0 (W0->Wb0, X0->xr0), clump 1 (W1->Wb1, X1->xr1) ----
    {
        const unsigned short* g0 = Wp + (size_t)lane * 8;
        const unsigned short* g1 = Wp + ((size_t)2048 + lane) * 8;
#pragma unroll
        for (int i = 0; i < 8; ++i) {
            int ub = wv * 512 + i * 64;
            gl_lds16(g0 + (size_t)ub * 8, Wb0 + ub * 8);
        }
        xa0 = *(const float4*)(xp_base);
        xb0 = *(const float4*)(xp_base + 4);
#pragma unroll
        for (int i = 0; i < 8; ++i) {
            int ub = wv * 512 + i * 64;
            gl_lds16(g1 + (size_t)ub * 8, Wb1 + ub * 8);
        }
        xa1 = *(const float4*)(xp_base + BK);
        xb1 = *(const float4*)(xp_base + BK + 4);
        ASM_VMCNT10(); SCHED_BAR();          // clump 0 complete; clump 1 in flight
        cvt_store(xa0, xb0, xh_dst, xl_dst); // X(0) -> LDS
        ASM_LGKM0();
        BARRIER();
    }

#define STEP(P, Q, S)                                                                       \
    {                                                                                       \
        const int s_ = (S);                                                                 \
        short8 ah[4], al[4], bh[4], bl[4];                                                  \
        _Pragma("unroll")                                                                   \
        for (int rf = 0; rf < 4; ++rf) {                                                    \
            int u = (lg * 64 + rf * 16 + lr) ^ (lg << 1);                                   \
            ah[rf] = *(const short8*)(Xh + u * 8);                                          \
            al[rf] = *(const short8*)(Xl + u * 8);                                          \
        }                                                                                   \
        _Pragma("unroll")                                                                   \
        for (int cf = 0; cf < 4; ++cf) {                                                    \
            int u = lg * 256 + wv * 64 + cf * 16 + lr;                                      \
            bh[cf] = *(const short8*)(Wb##P + u * 8);                                       \
            bl[cf] = *(const short8*)(Wb##P + (u + 1024) * 8);                              \
        }                                                                                   \
        ASM_LGKM0(); SCHED_BAR();                                                           \
        BARRIER();  /* #1: all waves finished reading X and Wb#P */                         \
        int sn_ = s_ + 2; if (sn_ > NSTEP - 1) sn_ = NSTEP - 1;                             \
        const unsigned short* gsrc_ = Wp + ((size_t)sn_ * 2048 + lane) * 8;                 \
        _Pragma("unroll")                                                                   \
        for (int i = 0; i < 8; ++i) {                                                       \
            int ub = wv * 512 + i * 64;                                                     \
            gl_lds16(gsrc_ + (size_t)ub * 8, Wb##P + ub * 8);                               \
        }                                                                                   \
        xa##P = *(const float4*)(xp_base + sn_ * BK);                                       \
        xb##P = *(const float4*)(xp_base + sn_ * BK + 4);                                   \
        ASM_VMCNT10(); SCHED_BAR();   /* clump s+1 done (W landed, X regs); s+2 in flight */\
        cvt_store(xa##Q, xb##Q, xh_dst, xl_dst);   /* X(s+1) -> LDS */                      \
        __builtin_amdgcn_s_setprio(1);                                                      \
        _Pragma("unroll")                                                                   \
        for (int cf = 0; cf < 4; ++cf) {                                                    \
            _Pragma("unroll")                                                               \
            for (int rf = 0; rf < 4; ++rf) {                                                \
                acc[rf][cf] = __builtin_amdgcn_mfma_f32_16x16x32_bf16(al[rf], bh[cf], acc[rf][cf], 0, 0, 0); \
                acc[rf][cf] = __builtin_amdgcn_mfma_f32_16x16x32_bf16(ah[rf], bl[cf], acc[rf][cf], 0, 0, 0); \
                acc[rf][cf] = __builtin_amdgcn_mfma_f32_16x16x32_bf16(ah[rf], bh[cf], acc[rf][cf], 0, 0, 0); \
            }                                                                               \
        }                                                                                   \
        __builtin_amdgcn_s_setprio(0);                                                      \
        ASM_LGKM0(); SCHED_BAR();                                                           \
        BARRIER();  /* #2 */                                                                \
    }

#pragma unroll 1
    for (int s2 = 0; s2 < NSTEP / 2; ++s2) {
        STEP(0, 1, 2 * s2);
        STEP(1, 0, 2 * s2 + 1);
    }
#undef STEP

    __syncthreads();   // full drain (vmcnt0 + lgkm0) before LDS alias reuse

    // epilogue aliases (X region only; gl_lds tail lands in Wb regions)
    float* Rv1    = (float*)smem;
    float* Rv2    = (float*)(smem + 1024);
    int*   Ri1    = (int*)  (smem + 2048);
    int*   rowIdx = (int*)  (smem + 3072);

    // --- per-row top-2 (C/D layout: col=lane&15, row=(lane>>4)*4+reg) ---
    float c2v[4];
#pragma unroll
    for (int cf = 0; cf < 4; ++cf) c2v[cf] = c2[wv * 64 + cf * 16 + lr];

#pragma unroll
    for (int rf = 0; rf < 4; ++rf) {
#pragma unroll
        for (int reg = 0; reg < 4; ++reg) {
            float v1 = 3.4e38f, v2 = 3.4e38f;
            int   c1 = 1 << 20;
#pragma unroll
            for (int cf = 0; cf < 4; ++cf) {
                float sc = acc[rf][cf][reg] + c2v[cf];
                int col = wv * 64 + cf * 16 + lr;
                if (sc < v1 || (sc == v1 && col < c1)) { v2 = v1; v1 = sc; c1 = col; }
                else if (sc < v2) v2 = sc;
            }
#pragma unroll
            for (int off = 1; off < 16; off <<= 1) {
                float ov1 = __shfl_xor(v1, off);
                float ov2 = __shfl_xor(v2, off);
                int   oc1 = __shfl_xor(c1, off);
                if (ov1 < v1 || (ov1 == v1 && oc1 < c1)) { v2 = fminf(v1, ov2); v1 = ov1; c1 = oc1; }
                else v2 = fminf(v2, ov1);
            }
            if (lr == 0) {
                int r = rf * 16 + lg * 4 + reg;
                Rv1[r * 4 + wv] = v1; Ri1[r * 4 + wv] = c1; Rv2[r * 4 + wv] = v2;
            }
        }
    }
    __syncthreads();

    if (t < BM) {
        float v1 = Rv1[t * 4], v2 = Rv2[t * 4];
        int   c1 = Ri1[t * 4];
#pragma unroll
        for (int g = 1; g < 4; ++g) {
            float bv = Rv1[t * 4 + g], bs = Rv2[t * 4 + g];
            int   bc = Ri1[t * 4 + g];
            if (bv < v1) { v2 = fminf(v1, bs); v1 = bv; c1 = bc; }
            else         { v2 = fminf(v2, bv); }
        }
        rowIdx[t] = c1;
        if (v2 - v1 < MARGIN_TH) {
            int pos = atomicAdd(counter, 1);
            list[pos] = row0 + t;
        }
    }
    __syncthreads();

    // --- gather + write: 64 rows x 512 f32, coalesced float4 ---
#pragma unroll
    for (int m = 0; m < 32; ++m) {
        int lin = m * 256 + t;            // 0..8191
        int r   = lin >> 7;               // 0..63
        int c4  = (lin & 127) * 4;
        float4 v = *(const float4*)(Tdec + (size_t)rowIdx[r] * DD + c4);
        *(float4*)(out + (size_t)(row0 + r) * DD + c4) = v;
    }
}

// ---------------- refine: fp64-exact re-decision for near-tie rows ----------------------
__global__ __launch_bounds__(256) void refine_kernel(const float* __restrict__ X,
                                                     const float* __restrict__ enc_w,
                                                     const float* __restrict__ enc_b,
                                                     const float* __restrict__ cb,
                                                     const float* __restrict__ Tdec,
                                                     float* __restrict__ out,
                                                     const int* __restrict__ counter,
                                                     const int* __restrict__ list) {
    int cnt = *counter;
    __shared__ double r0[DD];
    __shared__ double sv[256];
    __shared__ int    si[256];
    for (int it = blockIdx.x; it < cnt; it += gridDim.x) {
        int n = list[it];
        const float* xr = X + (size_t)n * DIN;
        for (int d = threadIdx.x; d < DD; d += 256) {
            double a0 = 0, a1 = 0, a2 = 0, a3 = 0;
            for (int j = 0; j < DIN; j += 4) {
                a0 += (double)xr[j]     * (double)enc_w[(size_t)(j)     * DD + d];
                a1 += (double)xr[j + 1] * (double)enc_w[(size_t)(j + 1) * DD + d];
                a2 += (double)xr[j + 2] * (double)enc_w[(size_t)(j + 2) * DD + d];
                a3 += (double)xr[j + 3] * (double)enc_w[(size_t)(j + 3) * DD + d];
            }
            r0[d] = (double)enc_b[d] + a0 + a1 + a2 + a3;
        }
        __syncthreads();
        int k = threadIdx.x;
        const float* ck = cb + (size_t)k * DD;
        double d0 = 0, d1 = 0, n0 = 0, n1 = 0;
        for (int d = 0; d < DD; d += 2) {
            double c0 = ck[d], c1 = ck[d + 1];
            d0 += r0[d] * c0;     n0 += c0 * c0;
            d1 += r0[d + 1] * c1; n1 += c1 * c1;
        }
        sv[k] = -2.0 * (d0 + d1) + (n0 + n1); si[k] = k;
        __syncthreads();
        for (int off = 128; off; off >>= 1) {
            if (k < off) {
                double a = sv[k], b = sv[k + off];
                if (b < a || (b == a && si[k + off] < si[k])) { sv[k] = b; si[k] = si[k + off]; }
            }
            __syncthreads();
        }
        int best = si[0];
        for (int c = threadIdx.x; c < DD; c += 256)
            out[(size_t)n * DD + c] = Tdec[(size_t)best * DD + c];
        __syncthreads();
    }
}

extern "C" void kernel_launch(void* const* d_in, const int* in_sizes, int n_in,
                              void* d_out, int out_size, void* d_ws, size_t ws_size,
                              hipStream_t stream) {
    const float* X     = (const float*)d_in[0];
    const float* enc_w = (const float*)d_in[1];
    const float* enc_b = (const float*)d_in[2];
    const float* cb    = (const float*)d_in[3];
    const float* dec_w = (const float*)d_in[4];
    const float* dec_b = (const float*)d_in[5];
    float* out = (float*)d_out;

    char* ws = (char*)d_ws;
    unsigned short* Wp = (unsigned short*)(ws + 0);          // 24*2048*8*2B = 786432
    float* c2      = (float*)(ws + 786432);                  // 1024
    float* Tdec    = (float*)(ws + 787456);                  // 524288
    int*   counter = (int*)  (ws + 1311744);                 // 4 (+pad)
    int*   list    = (int*)  (ws + 1311776);                 // near-tie rows

    hipLaunchKernelGGL(w2_kernel,    dim3(768),       dim3(256), 0, stream,
                       enc_w, enc_b, cb, Wp, c2, counter);
    hipLaunchKernelGGL(chain_kernel, dim3(256),       dim3(256), 0, stream,
                       cb, dec_w, dec_b, Tdec);
    hipLaunchKernelGGL(bulk_kernel,  dim3(NROWS / BM), dim3(256), 0, stream,
                       X, Wp, c2, Tdec, out, counter, list);
    hipLaunchKernelGGL(refine_kernel, dim3(1024),     dim3(256), 0, stream,
                       X, enc_w, enc_b, cb, Tdec, out, counter, list);
}

// Round 5
// 459.501 us; speedup vs baseline: 1.2016x; 1.2016x over previous
//
#include <hip/hip_runtime.h>
#include <hip/hip_bf16.h>

#define NROWS 131072
#define DIN   768
#define DD    512
#define KK    256

#define BM    64
#define BK    32
#define NSTEP 24            // DIN/BK
#define MARGIN_TH 1e-3f

typedef __attribute__((ext_vector_type(8))) short  short8;
typedef __attribute__((ext_vector_type(8))) unsigned short ushort8;
typedef __attribute__((ext_vector_type(4))) float  f32x4;

__device__ __forceinline__ unsigned short f2bf_rn(float x) {
    unsigned int u = __float_as_uint(x);
    unsigned int r = (u + 0x7fffu + ((u >> 16) & 1u)) >> 16;   // RNE
    return (unsigned short)r;
}
__device__ __forceinline__ float bf2f(unsigned short h) {
    return __uint_as_float(((unsigned int)h) << 16);
}

__device__ __forceinline__ void cvt_store(float4 a, float4 b,
                                          unsigned short* hd, unsigned short* ldst) {
    ushort8 hv, lv;
#pragma unroll
    for (int j = 0; j < 4; ++j) {
        unsigned short h = f2bf_rn(a[j]);
        hv[j] = h; lv[j] = f2bf_rn(a[j] - bf2f(h));
    }
#pragma unroll
    for (int j = 0; j < 4; ++j) {
        unsigned short h = f2bf_rn(b[j]);
        hv[j + 4] = h; lv[j + 4] = f2bf_rn(b[j] - bf2f(h));
    }
    *(ushort8*)hd = hv;
    *(ushort8*)ldst = lv;
}

// ---------------- w2: W2 = -2*enc_w@cb0^T -> bf16 hi/lo in bulk tile order; c2 ----------
// grid 768 (one block per din row), 256 thr. Wave wv: cols [wv*64, wv*64+64), 4-col
// interleaved fp32 partial dots + 4 pipelined shuffle-reduce chains.
// Wp element layout: Wp[(s*2048 + lg*256 + col)*8 + jj] (hi), +1024 units (lo);
// din = s*32 + lg*8 + jj.
__global__ __launch_bounds__(256) void w2_kernel(const float* __restrict__ enc_w,
                                                 const float* __restrict__ enc_b,
                                                 const float* __restrict__ cb,
                                                 unsigned short* __restrict__ Wp,
                                                 float* __restrict__ c2,
                                                 int* __restrict__ counter) {
    int jrow = blockIdx.x;               // din 0..767
    int t = threadIdx.x;
    int lane = t & 63, wv = t >> 6;
    __shared__ float wrow[DD];
    for (int d = t; d < DD; d += 256) wrow[d] = enc_w[(size_t)jrow * DD + d];
    __syncthreads();

    size_t ubase = (size_t)(jrow >> 5) * 2048 + (size_t)((jrow >> 3) & 3) * 256;
    int jj = jrow & 7;

    for (int c4 = 0; c4 < 16; ++c4) {
        int col0 = wv * 64 + c4 * 4;
        const float* C0 = cb + (size_t)col0 * DD;
        const float* C1 = C0 + DD;
        const float* C2 = C0 + 2 * DD;
        const float* C3 = C0 + 3 * DD;
        float p0 = 0, p1 = 0, p2 = 0, p3 = 0;
#pragma unroll
        for (int i = 0; i < 8; ++i) {
            int d = lane + 64 * i;
            float w = wrow[d];
            p0 = fmaf(w, C0[d], p0);
            p1 = fmaf(w, C1[d], p1);
            p2 = fmaf(w, C2[d], p2);
            p3 = fmaf(w, C3[d], p3);
        }
#pragma unroll
        for (int off = 1; off < 64; off <<= 1) {
            p0 += __shfl_xor(p0, off);
            p1 += __shfl_xor(p1, off);
            p2 += __shfl_xor(p2, off);
            p3 += __shfl_xor(p3, off);
        }
        if (lane == 0) {
            float pv[4] = {p0, p1, p2, p3};
#pragma unroll
            for (int q = 0; q < 4; ++q) {
                float w = -2.0f * pv[q];
                unsigned short h = f2bf_rn(w);
                unsigned short l = f2bf_rn(w - bf2f(h));
                size_t u = ubase + (size_t)(col0 + q);
                Wp[u * 8 + jj]          = h;
                Wp[(u + 1024) * 8 + jj] = l;
            }
        }
    }

    if (jrow == 0) {
        __syncthreads();
        for (int d = t; d < DD; d += 256) wrow[d] = enc_b[d];   // reuse LDS for bias
        __syncthreads();
        for (int c4 = 0; c4 < 16; ++c4) {
            int col0 = wv * 64 + c4 * 4;
            const float* C0 = cb + (size_t)col0 * DD;
            const float* C1 = C0 + DD;
            const float* C2 = C0 + 2 * DD;
            const float* C3 = C0 + 3 * DD;
            float b0 = 0, b1 = 0, b2 = 0, b3 = 0, n0 = 0, n1 = 0, n2 = 0, n3 = 0;
#pragma unroll
            for (int i = 0; i < 8; ++i) {
                int d = lane + 64 * i;
                float b = wrow[d];
                float c0v = C0[d], c1v = C1[d], c2v = C2[d], c3v = C3[d];
                b0 = fmaf(b, c0v, b0); n0 = fmaf(c0v, c0v, n0);
                b1 = fmaf(b, c1v, b1); n1 = fmaf(c1v, c1v, n1);
                b2 = fmaf(b, c2v, b2); n2 = fmaf(c2v, c2v, n2);
                b3 = fmaf(b, c3v, b3); n3 = fmaf(c3v, c3v, n3);
            }
#pragma unroll
            for (int off = 1; off < 64; off <<= 1) {
                b0 += __shfl_xor(b0, off); n0 += __shfl_xor(n0, off);
                b1 += __shfl_xor(b1, off); n1 += __shfl_xor(n1, off);
                b2 += __shfl_xor(b2, off); n2 += __shfl_xor(n2, off);
                b3 += __shfl_xor(b3, off); n3 += __shfl_xor(n3, off);
            }
            if (lane == 0) {
                c2[col0]     = -2.0f * b0 + n0;
                c2[col0 + 1] = -2.0f * b1 + n1;
                c2[col0 + 2] = -2.0f * b2 + n2;
                c2[col0 + 3] = -2.0f * b3 + n3;
            }
        }
        if (t == 0) *counter = 0;
    }
}

// ---------------- chain: per k walk 3-layer argmin chain + decoder GEMV -----------------
// grid 256 (one block per k), 256 thr. Wave wv scores 64 cols, 4-col interleaved.
__global__ __launch_bounds__(256) void chain_kernel(const float* __restrict__ cb,
                                                    const float* __restrict__ dec_w,
                                                    const float* __restrict__ dec_b,
                                                    float* __restrict__ Tdec) {
    int k = blockIdx.x;
    int t = threadIdx.x;
    int lane = t & 63, wv = t >> 6;
    __shared__ float  q[DD];
    __shared__ float  Tsum[DD];
    __shared__ double wbest[4];
    __shared__ int    wbesti[4];
    __shared__ int    sel;

    for (int d = t; d < DD; d += 256) {
        float v = cb[(size_t)k * DD + d];
        q[d] = v; Tsum[d] = v;
    }

    for (int l = 1; l < 4; ++l) {
        __syncthreads();
        const float* C = cb + (size_t)l * KK * DD;
        double best = 1e300; int bi = 1 << 20;
        for (int c4 = 0; c4 < 16; ++c4) {
            int col0 = wv * 64 + c4 * 4;
            const float* C0 = C + (size_t)col0 * DD;
            const float* C1 = C0 + DD;
            const float* C2 = C0 + 2 * DD;
            const float* C3 = C0 + 3 * DD;
            float p0 = 0, p1 = 0, p2 = 0, p3 = 0, n0 = 0, n1 = 0, n2 = 0, n3 = 0;
#pragma unroll
            for (int i = 0; i < 8; ++i) {
                int d = lane + 64 * i;
                float qq = q[d];
                float c0v = C0[d], c1v = C1[d], c2v = C2[d], c3v = C3[d];
                p0 = fmaf(qq, c0v, p0); n0 = fmaf(c0v, c0v, n0);
                p1 = fmaf(qq, c1v, p1); n1 = fmaf(c1v, c1v, n1);
                p2 = fmaf(qq, c2v, p2); n2 = fmaf(c2v, c2v, n2);
                p3 = fmaf(qq, c3v, p3); n3 = fmaf(c3v, c3v, n3);
            }
            double s0 = -2.0 * (double)p0 + (double)n0;
            double s1 = -2.0 * (double)p1 + (double)n1;
            double s2 = -2.0 * (double)p2 + (double)n2;
            double s3 = -2.0 * (double)p3 + (double)n3;
#pragma unroll
            for (int off = 1; off < 64; off <<= 1) {
                s0 += __shfl_xor(s0, off);
                s1 += __shfl_xor(s1, off);
                s2 += __shfl_xor(s2, off);
                s3 += __shfl_xor(s3, off);
            }
            if (s0 < best) { best = s0; bi = col0; }
            if (s1 < best) { best = s1; bi = col0 + 1; }
            if (s2 < best) { best = s2; bi = col0 + 2; }
            if (s3 < best) { best = s3; bi = col0 + 3; }
        }
        if (lane == 0) { wbest[wv] = best; wbesti[wv] = bi; }
        __syncthreads();
        if (t == 0) {
            double bv = wbest[0]; int bidx = wbesti[0];
            for (int g = 1; g < 4; ++g)
                if (wbest[g] < bv || (wbest[g] == bv && wbesti[g] < bidx)) { bv = wbest[g]; bidx = wbesti[g]; }
            sel = bidx;
        }
        __syncthreads();
        const float* Cs = C + (size_t)sel * DD;
        for (int d = t; d < DD; d += 256) {
            float v = Cs[d];
            q[d] = v; Tsum[d] += v;
        }
    }
    __syncthreads();
    for (int n = t; n < DD; n += 256) {
        double a0 = 0, a1 = 0, a2 = 0, a3 = 0;
        for (int d = 0; d < DD; d += 4) {
            a0 += (double)Tsum[d]     * (double)dec_w[(size_t)(d)     * DD + n];
            a1 += (double)Tsum[d + 1] * (double)dec_w[(size_t)(d + 1) * DD + n];
            a2 += (double)Tsum[d + 2] * (double)dec_w[(size_t)(d + 2) * DD + n];
            a3 += (double)Tsum[d + 3] * (double)dec_w[(size_t)(d + 3) * DD + n];
        }
        Tdec[(size_t)k * DD + n] = (float)((double)dec_b[n] + a0 + a1 + a2 + a3);
    }
}

// ---------------- bulk: W-in-registers MFMA, X double-buffered LDS, 1 barrier/step ------
// grid 2048, block 256 (4 waves). Block tile 64 rows x 256 cols; wave tile 64x64 (cg=wv).
// W frags loaded straight from L2-resident Wp (no cross-wave W reuse -> no LDS staging).
__global__ __launch_bounds__(256, 3) void bulk_kernel(const float* __restrict__ X,
                                                      const unsigned short* __restrict__ Wp,
                                                      const float* __restrict__ c2,
                                                      const float* __restrict__ Tdec,
                                                      float* __restrict__ out,
                                                      int* __restrict__ counter,
                                                      int* __restrict__ list) {
    __shared__ __align__(16) unsigned short Xh[2][2048];   // 2 x 4KB (256 units x 16B)
    __shared__ __align__(16) unsigned short Xl[2][2048];   // 2 x 4KB
    __shared__ float Rv1[BM * 4];
    __shared__ float Rv2[BM * 4];
    __shared__ int   Ri1[BM * 4];
    __shared__ int   rowIdx[BM];

    const int t    = threadIdx.x;
    const int lane = t & 63;
    const int wv   = t >> 6;        // col-group 0..3 (64 cols each)
    const int lr   = lane & 15;
    const int lg   = lane >> 4;
    const int row0 = blockIdx.x * BM;

    f32x4 acc[4][4];
#pragma unroll
    for (int rf = 0; rf < 4; ++rf)
#pragma unroll
        for (int cf = 0; cf < 4; ++cf) acc[rf][cf] = (f32x4){0.f, 0.f, 0.f, 0.f};

    // X staging: thread t handles row=t>>2, k-subchunk=(t&3)*8
    const int xrow = t >> 2, xsub = t & 3;
    const float* xp_base = X + (size_t)(row0 + xrow) * DIN + xsub * 8;
    const int xu = (xsub * 64 + xrow) ^ (xsub << 1);   // XOR-swizzled unit (write side)

    // prologue: stage X(0) into buffer 0
    {
        float4 a = *(const float4*)xp_base;
        float4 b = *(const float4*)(xp_base + 4);
        cvt_store(a, b, &Xh[0][xu * 8], &Xl[0][xu * 8]);
    }
    __syncthreads();

#define HALF(P, S)                                                                          \
    {                                                                                       \
        const int s_ = (S);                                                                 \
        float4 nxa, nxb;                                                                    \
        if (s_ + 1 < NSTEP) {                                                               \
            nxa = *(const float4*)(xp_base + (s_ + 1) * BK);                                \
            nxb = *(const float4*)(xp_base + (s_ + 1) * BK + 4);                            \
        }                                                                                   \
        short8 ah[4], al[4], bh[4], bl[4];                                                  \
        const unsigned short* wbase = Wp + (size_t)s_ * 16384;                              \
        _Pragma("unroll")                                                                   \
        for (int cf = 0; cf < 4; ++cf) {                                                    \
            int u = lg * 256 + wv * 64 + cf * 16 + lr;                                      \
            bh[cf] = *(const short8*)(wbase + (size_t)u * 8);                               \
            bl[cf] = *(const short8*)(wbase + (size_t)(u + 1024) * 8);                      \
        }                                                                                   \
        _Pragma("unroll")                                                                   \
        for (int rf = 0; rf < 4; ++rf) {                                                    \
            int u = (lg * 64 + rf * 16 + lr) ^ (lg << 1);                                   \
            ah[rf] = *(const short8*)&Xh[P][u * 8];                                         \
            al[rf] = *(const short8*)&Xl[P][u * 8];                                         \
        }                                                                                   \
        if (s_ + 1 < NSTEP)                                                                 \
            cvt_store(nxa, nxb, &Xh[P ^ 1][xu * 8], &Xl[P ^ 1][xu * 8]);                    \
        _Pragma("unroll")                                                                   \
        for (int cf = 0; cf < 4; ++cf) {                                                    \
            _Pragma("unroll")                                                               \
            for (int rf = 0; rf < 4; ++rf) {                                                \
                acc[rf][cf] = __builtin_amdgcn_mfma_f32_16x16x32_bf16(al[rf], bh[cf], acc[rf][cf], 0, 0, 0); \
                acc[rf][cf] = __builtin_amdgcn_mfma_f32_16x16x32_bf16(ah[rf], bl[cf], acc[rf][cf], 0, 0, 0); \
                acc[rf][cf] = __builtin_amdgcn_mfma_f32_16x16x32_bf16(ah[rf], bh[cf], acc[rf][cf], 0, 0, 0); \
            }                                                                               \
        }                                                                                   \
        __syncthreads();                                                                    \
    }

#pragma unroll 1
    for (int s2 = 0; s2 < NSTEP / 2; ++s2) {
        HALF(0, 2 * s2);
        HALF(1, 2 * s2 + 1);
    }
#undef HALF

    // --- epilogue: per-row top-2 (C/D layout: col=lane&15, row=(lane>>4)*4+reg) ---
    float c2v[4];
#pragma unroll
    for (int cf = 0; cf < 4; ++cf) c2v[cf] = c2[wv * 64 + cf * 16 + lr];

#pragma unroll
    for (int rf = 0; rf < 4; ++rf) {
#pragma unroll
        for (int reg = 0; reg < 4; ++reg) {
            float v1 = 3.4e38f, v2 = 3.4e38f;
            int   c1 = 1 << 20;
#pragma unroll
            for (int cf = 0; cf < 4; ++cf) {
                float sc = acc[rf][cf][reg] + c2v[cf];
                int col = wv * 64 + cf * 16 + lr;
                if (sc < v1 || (sc == v1 && col < c1)) { v2 = v1; v1 = sc; c1 = col; }
                else if (sc < v2) v2 = sc;
            }
#pragma unroll
            for (int off = 1; off < 16; off <<= 1) {
                float ov1 = __shfl_xor(v1, off);
                float ov2 = __shfl_xor(v2, off);
                int   oc1 = __shfl_xor(c1, off);
                if (ov1 < v1 || (ov1 == v1 && oc1 < c1)) { v2 = fminf(v1, ov2); v1 = ov1; c1 = oc1; }
                else v2 = fminf(v2, ov1);
            }
            if (lr == 0) {
                int r = rf * 16 + lg * 4 + reg;
                Rv1[r * 4 + wv] = v1; Ri1[r * 4 + wv] = c1; Rv2[r * 4 + wv] = v2;
            }
        }
    }
    __syncthreads();

    if (t < BM) {
        float v1 = Rv1[t * 4], v2 = Rv2[t * 4];
        int   c1 = Ri1[t * 4];
#pragma unroll
        for (int g = 1; g < 4; ++g) {
            float bv = Rv1[t * 4 + g], bs = Rv2[t * 4 + g];
            int   bc = Ri1[t * 4 + g];
            if (bv < v1) { v2 = fminf(v1, bs); v1 = bv; c1 = bc; }
            else         { v2 = fminf(v2, bv); }
        }
        rowIdx[t] = c1;
        if (v2 - v1 < MARGIN_TH) {
            int pos = atomicAdd(counter, 1);
            list[pos] = row0 + t;
        }
    }
    __syncthreads();

    // --- gather + write: 64 rows x 512 f32, coalesced float4 ---
#pragma unroll
    for (int m = 0; m < 32; ++m) {
        int lin = m * 256 + t;            // 0..8191
        int r   = lin >> 7;               // 0..63
        int c4  = (lin & 127) * 4;
        float4 v = *(const float4*)(Tdec + (size_t)rowIdx[r] * DD + c4);
        *(float4*)(out + (size_t)(row0 + r) * DD + c4) = v;
    }
}

// ---------------- refine: fp64-exact re-decision for near-tie rows ----------------------
__global__ __launch_bounds__(256) void refine_kernel(const float* __restrict__ X,
                                                     const float* __restrict__ enc_w,
                                                     const float* __restrict__ enc_b,
                                                     const float* __restrict__ cb,
                                                     const float* __restrict__ Tdec,
                                                     float* __restrict__ out,
                                                     const int* __restrict__ counter,
                                                     const int* __restrict__ list) {
    int cnt = *counter;
    __shared__ double r0[DD];
    __shared__ double sv[256];
    __shared__ int    si[256];
    for (int it = blockIdx.x; it < cnt; it += gridDim.x) {
        int n = list[it];
        const float* xr = X + (size_t)n * DIN;
        for (int d = threadIdx.x; d < DD; d += 256) {
            double a0 = 0, a1 = 0, a2 = 0, a3 = 0;
            for (int j = 0; j < DIN; j += 4) {
                a0 += (double)xr[j]     * (double)enc_w[(size_t)(j)     * DD + d];
                a1 += (double)xr[j + 1] * (double)enc_w[(size_t)(j + 1) * DD + d];
                a2 += (double)xr[j + 2] * (double)enc_w[(size_t)(j + 2) * DD + d];
                a3 += (double)xr[j + 3] * (double)enc_w[(size_t)(j + 3) * DD + d];
            }
            r0[d] = (double)enc_b[d] + a0 + a1 + a2 + a3;
        }
        __syncthreads();
        int k = threadIdx.x;
        const float* ck = cb + (size_t)k * DD;
        double d0 = 0, d1 = 0, n0 = 0, n1 = 0;
        for (int d = 0; d < DD; d += 2) {
            double c0 = ck[d], c1 = ck[d + 1];
            d0 += r0[d] * c0;     n0 += c0 * c0;
            d1 += r0[d + 1] * c1; n1 += c1 * c1;
        }
        sv[k] = -2.0 * (d0 + d1) + (n0 + n1); si[k] = k;
        __syncthreads();
        for (int off = 128; off; off >>= 1) {
            if (k < off) {
                double a = sv[k], b = sv[k + off];
                if (b < a || (b == a && si[k + off] < si[k])) { sv[k] = b; si[k] = si[k + off]; }
            }
            __syncthreads();
        }
        int best = si[0];
        for (int c = threadIdx.x; c < DD; c += 256)
            out[(size_t)n * DD + c] = Tdec[(size_t)best * DD + c];
        __syncthreads();
    }
}

extern "C" void kernel_launch(void* const* d_in, const int* in_sizes, int n_in,
                              void* d_out, int out_size, void* d_ws, size_t ws_size,
                              hipStream_t stream) {
    const float* X     = (const float*)d_in[0];
    const float* enc_w = (const float*)d_in[1];
    const float* enc_b = (const float*)d_in[2];
    const float* cb    = (const float*)d_in[3];
    const float* dec_w = (const float*)d_in[4];
    const float* dec_b = (const float*)d_in[5];
    float* out = (float*)d_out;

    char* ws = (char*)d_ws;
    unsigned short* Wp = (unsigned short*)(ws + 0);          // 24*2048*8*2B = 786432
    float* c2      = (float*)(ws + 786432);                  // 1024
    float* Tdec    = (float*)(ws + 787456);                  // 524288
    int*   counter = (int*)  (ws + 1311744);                 // 4 (+pad)
    int*   list    = (int*)  (ws + 1311776);                 // near-tie rows

    hipLaunchKernelGGL(w2_kernel,    dim3(768),        dim3(256), 0, stream,
                       enc_w, enc_b, cb, Wp, c2, counter);
    hipLaunchKernelGGL(chain_kernel, dim3(256),        dim3(256), 0, stream,
                       cb, dec_w, dec_b, Tdec);
    hipLaunchKernelGGL(bulk_kernel,  dim3(NROWS / BM), dim3(256), 0, stream,
                       X, Wp, c2, Tdec, out, counter, list);
    hipLaunchKernelGGL(refine_kernel, dim3(1024),      dim3(256), 0, stream,
                       X, enc_w, enc_b, cb, Tdec, out, counter, list);
}

// Round 7
// 371.259 us; speedup vs baseline: 1.4872x; 1.2377x over previous
//
#include <hip/hip_runtime.h>
#include <hip/hip_bf16.h>

#define NROWS 131072
#define DIN   768
#define DD    512
#define KK    256

#define BM    64
#define BK    32
#define NSTEP 24            // DIN/BK
#define MARGIN_TH 1e-3f

typedef __attribute__((ext_vector_type(8))) short  short8;
typedef __attribute__((ext_vector_type(8))) unsigned short ushort8;
typedef __attribute__((ext_vector_type(4))) float  f32x4;

__device__ __forceinline__ unsigned short f2bf_rn(float x) {
    unsigned int u = __float_as_uint(x);
    unsigned int r = (u + 0x7fffu + ((u >> 16) & 1u)) >> 16;   // RNE
    return (unsigned short)r;
}
__device__ __forceinline__ float bf2f(unsigned short h) {
    return __uint_as_float(((unsigned int)h) << 16);
}

__device__ __forceinline__ void cvt_store(f32x4 a, f32x4 b,
                                          unsigned short* hd, unsigned short* ldst) {
    ushort8 hv, lv;
#pragma unroll
    for (int j = 0; j < 4; ++j) {
        unsigned short h = f2bf_rn(a[j]);
        hv[j] = h; lv[j] = f2bf_rn(a[j] - bf2f(h));
    }
#pragma unroll
    for (int j = 0; j < 4; ++j) {
        unsigned short h = f2bf_rn(b[j]);
        hv[j + 4] = h; lv[j + 4] = f2bf_rn(b[j] - bf2f(h));
    }
    *(ushort8*)hd = hv;
    *(ushort8*)ldst = lv;
}

// ---------------- pre: fused w2 (blocks 0..767) + chain/Tdec (blocks 768..1023) ---------
// w2: W2 = -2*enc_w@cb0^T -> bf16 hi/lo in bulk tile order; c2; counter=0.
// Wp element layout: Wp[(s*2048 + lg*256 + col)*8 + jj] (hi), +1024 units (lo);
// din = s*32 + lg*8 + jj.
// chain: per k walk 3-layer fp64-decision argmin chain + fp64 decoder GEMV -> Tdec[k].
__global__ __launch_bounds__(256) void pre_kernel(const float* __restrict__ enc_w,
                                                  const float* __restrict__ enc_b,
                                                  const float* __restrict__ cb,
                                                  const float* __restrict__ dec_w,
                                                  const float* __restrict__ dec_b,
                                                  unsigned short* __restrict__ Wp,
                                                  float* __restrict__ c2,
                                                  float* __restrict__ Tdec,
                                                  int* __restrict__ counter) {
    int t = threadIdx.x;
    int lane = t & 63, wv = t >> 6;

    if (blockIdx.x < 768) {
        // ================= w2 role =================
        int jrow = blockIdx.x;               // din 0..767
        __shared__ float wrow[DD];
        for (int d = t; d < DD; d += 256) wrow[d] = enc_w[(size_t)jrow * DD + d];
        __syncthreads();

        size_t ubase = (size_t)(jrow >> 5) * 2048 + (size_t)((jrow >> 3) & 3) * 256;
        int jj = jrow & 7;

        for (int c4 = 0; c4 < 16; ++c4) {
            int col0 = wv * 64 + c4 * 4;
            const float* C0 = cb + (size_t)col0 * DD;
            const float* C1 = C0 + DD;
            const float* C2 = C0 + 2 * DD;
            const float* C3 = C0 + 3 * DD;
            float p0 = 0, p1 = 0, p2 = 0, p3 = 0;
#pragma unroll
            for (int i = 0; i < 8; ++i) {
                int d = lane + 64 * i;
                float w = wrow[d];
                p0 = fmaf(w, C0[d], p0);
                p1 = fmaf(w, C1[d], p1);
                p2 = fmaf(w, C2[d], p2);
                p3 = fmaf(w, C3[d], p3);
            }
#pragma unroll
            for (int off = 1; off < 64; off <<= 1) {
                p0 += __shfl_xor(p0, off);
                p1 += __shfl_xor(p1, off);
                p2 += __shfl_xor(p2, off);
                p3 += __shfl_xor(p3, off);
            }
            if (lane == 0) {
                float pv[4] = {p0, p1, p2, p3};
#pragma unroll
                for (int q = 0; q < 4; ++q) {
                    float w = -2.0f * pv[q];
                    unsigned short h = f2bf_rn(w);
                    unsigned short l = f2bf_rn(w - bf2f(h));
                    size_t u = ubase + (size_t)(col0 + q);
                    Wp[u * 8 + jj]          = h;
                    Wp[(u + 1024) * 8 + jj] = l;
                }
            }
        }

        if (jrow == 0) {
            __syncthreads();
            for (int d = t; d < DD; d += 256) wrow[d] = enc_b[d];
            __syncthreads();
            for (int c4 = 0; c4 < 16; ++c4) {
                int col0 = wv * 64 + c4 * 4;
                const float* C0 = cb + (size_t)col0 * DD;
                const float* C1 = C0 + DD;
                const float* C2 = C0 + 2 * DD;
                const float* C3 = C0 + 3 * DD;
                float b0 = 0, b1 = 0, b2 = 0, b3 = 0, n0 = 0, n1 = 0, n2 = 0, n3 = 0;
#pragma unroll
                for (int i = 0; i < 8; ++i) {
                    int d = lane + 64 * i;
                    float b = wrow[d];
                    float c0v = C0[d], c1v = C1[d], c2v = C2[d], c3v = C3[d];
                    b0 = fmaf(b, c0v, b0); n0 = fmaf(c0v, c0v, n0);
                    b1 = fmaf(b, c1v, b1); n1 = fmaf(c1v, c1v, n1);
                    b2 = fmaf(b, c2v, b2); n2 = fmaf(c2v, c2v, n2);
                    b3 = fmaf(b, c3v, b3); n3 = fmaf(c3v, c3v, n3);
                }
#pragma unroll
                for (int off = 1; off < 64; off <<= 1) {
                    b0 += __shfl_xor(b0, off); n0 += __shfl_xor(n0, off);
                    b1 += __shfl_xor(b1, off); n1 += __shfl_xor(n1, off);
                    b2 += __shfl_xor(b2, off); n2 += __shfl_xor(n2, off);
                    b3 += __shfl_xor(b3, off); n3 += __shfl_xor(n3, off);
                }
                if (lane == 0) {
                    c2[col0]     = -2.0f * b0 + n0;
                    c2[col0 + 1] = -2.0f * b1 + n1;
                    c2[col0 + 2] = -2.0f * b2 + n2;
                    c2[col0 + 3] = -2.0f * b3 + n3;
                }
            }
            if (t == 0) *counter = 0;
        }
    } else {
        // ================= chain role =================
        int k = blockIdx.x - 768;
        __shared__ float  q[DD];
        __shared__ float  Tsum[DD];
        __shared__ double wbest[4];
        __shared__ int    wbesti[4];
        __shared__ int    sel;

        for (int d = t; d < DD; d += 256) {
            float v = cb[(size_t)k * DD + d];
            q[d] = v; Tsum[d] = v;
        }

        for (int l = 1; l < 4; ++l) {
            __syncthreads();
            const float* C = cb + (size_t)l * KK * DD;
            double best = 1e300; int bi = 1 << 20;
            for (int c4 = 0; c4 < 16; ++c4) {
                int col0 = wv * 64 + c4 * 4;
                const float* C0 = C + (size_t)col0 * DD;
                const float* C1 = C0 + DD;
                const float* C2 = C0 + 2 * DD;
                const float* C3 = C0 + 3 * DD;
                float p0 = 0, p1 = 0, p2 = 0, p3 = 0, n0 = 0, n1 = 0, n2 = 0, n3 = 0;
#pragma unroll
                for (int i = 0; i < 8; ++i) {
                    int d = lane + 64 * i;
                    float qq = q[d];
                    float c0v = C0[d], c1v = C1[d], c2v = C2[d], c3v = C3[d];
                    p0 = fmaf(qq, c0v, p0); n0 = fmaf(c0v, c0v, n0);
                    p1 = fmaf(qq, c1v, p1); n1 = fmaf(c1v, c1v, n1);
                    p2 = fmaf(qq, c2v, p2); n2 = fmaf(c2v, c2v, n2);
                    p3 = fmaf(qq, c3v, p3); n3 = fmaf(c3v, c3v, n3);
                }
                double s0 = -2.0 * (double)p0 + (double)n0;
                double s1 = -2.0 * (double)p1 + (double)n1;
                double s2 = -2.0 * (double)p2 + (double)n2;
                double s3 = -2.0 * (double)p3 + (double)n3;
#pragma unroll
                for (int off = 1; off < 64; off <<= 1) {
                    s0 += __shfl_xor(s0, off);
                    s1 += __shfl_xor(s1, off);
                    s2 += __shfl_xor(s2, off);
                    s3 += __shfl_xor(s3, off);
                }
                if (s0 < best) { best = s0; bi = col0; }
                if (s1 < best) { best = s1; bi = col0 + 1; }
                if (s2 < best) { best = s2; bi = col0 + 2; }
                if (s3 < best) { best = s3; bi = col0 + 3; }
            }
            if (lane == 0) { wbest[wv] = best; wbesti[wv] = bi; }
            __syncthreads();
            if (t == 0) {
                double bv = wbest[0]; int bidx = wbesti[0];
                for (int g = 1; g < 4; ++g)
                    if (wbest[g] < bv || (wbest[g] == bv && wbesti[g] < bidx)) { bv = wbest[g]; bidx = wbesti[g]; }
                sel = bidx;
            }
            __syncthreads();
            const float* Cs = C + (size_t)sel * DD;
            for (int d = t; d < DD; d += 256) {
                float v = Cs[d];
                q[d] = v; Tsum[d] += v;
            }
        }
        __syncthreads();
        for (int n = t; n < DD; n += 256) {
            double a0 = 0, a1 = 0, a2 = 0, a3 = 0;
            for (int d = 0; d < DD; d += 4) {
                a0 += (double)Tsum[d]     * (double)dec_w[(size_t)(d)     * DD + n];
                a1 += (double)Tsum[d + 1] * (double)dec_w[(size_t)(d + 1) * DD + n];
                a2 += (double)Tsum[d + 2] * (double)dec_w[(size_t)(d + 2) * DD + n];
                a3 += (double)Tsum[d + 3] * (double)dec_w[(size_t)(d + 3) * DD + n];
            }
            Tdec[(size_t)k * DD + n] = (float)((double)dec_b[n] + a0 + a1 + a2 + a3);
        }
    }
}

// ---------------- bulk: reg-pipelined MFMA (X 2-deep, W 1-deep), 1 barrier/step ---------
// grid 2048, block 256 (4 waves). Block tile 64 rows x 256 cols; wave tile 64x64 (cg=wv).
// Step s: read X(s) frags from LDS[s&1] | cvt X(s+1) regs->LDS[(s+1)&1] | issue X(s+2)
// loads | issue W(s+1) loads | MFMA with W(s) regs (compiler emits counted vmcnt) | barrier.
__global__ __launch_bounds__(256, 2) void bulk_kernel(const float* __restrict__ X,
                                                      const unsigned short* __restrict__ Wp,
                                                      const float* __restrict__ c2,
                                                      const float* __restrict__ Tdec,
                                                      float* __restrict__ out,
                                                      int* __restrict__ counter,
                                                      int* __restrict__ list) {
    __shared__ __align__(16) unsigned short Xh[2][2048];   // 2 x 4KB (256 units x 16B)
    __shared__ __align__(16) unsigned short Xl[2][2048];   // 2 x 4KB
    __shared__ float Rv1[BM * 4];
    __shared__ float Rv2[BM * 4];
    __shared__ int   Ri1[BM * 4];
    __shared__ int   rowIdx[BM];

    const int t    = threadIdx.x;
    const int lane = t & 63;
    const int wv   = t >> 6;        // col-group 0..3 (64 cols each)
    const int lr   = lane & 15;
    const int lg   = lane >> 4;
    const int row0 = blockIdx.x * BM;

    f32x4 acc[4][4];
#pragma unroll
    for (int rf = 0; rf < 4; ++rf)
#pragma unroll
        for (int cf = 0; cf < 4; ++cf) acc[rf][cf] = (f32x4){0.f, 0.f, 0.f, 0.f};

    // X staging: thread t handles row=t>>2, k-subchunk=(t&3)*8
    const int xrow = t >> 2, xsub = t & 3;
    const float* xp_base = X + (size_t)(row0 + xrow) * DIN + xsub * 8;
    const int xu = (xsub * 64 + xrow) ^ (xsub << 1);   // XOR-swizzled unit (write side)

    // W frag lane-base: u = lg*256 + wv*64 + cf*16 + lr; hi at u*8, lo at (u+1024)*8
    const unsigned short* wlane = Wp + (size_t)(lg * 256 + wv * 64 + lr) * 8;

    f32x4 nxa[2], nxb[2];
    short8 wh[2][4], wl[2][4];

    // ---- prologue ----
    {
        f32x4 a = __builtin_nontemporal_load((const f32x4*)xp_base);
        f32x4 b = __builtin_nontemporal_load((const f32x4*)(xp_base + 4));
        cvt_store(a, b, &Xh[0][xu * 8], &Xl[0][xu * 8]);
        // issue X(1)
        nxa[1] = __builtin_nontemporal_load((const f32x4*)(xp_base + BK));
        nxb[1] = __builtin_nontemporal_load((const f32x4*)(xp_base + BK + 4));
        // issue W(0)
#pragma unroll
        for (int cf = 0; cf < 4; ++cf) {
            wh[0][cf] = *(const short8*)(wlane + cf * 128);
            wl[0][cf] = *(const short8*)(wlane + cf * 128 + 8192);
        }
    }
    __syncthreads();

#define HALF(P, S)                                                                          \
    {                                                                                       \
        const int s_ = (S);                                                                 \
        /* read X(s) fragments from LDS[P] */                                               \
        short8 ah[4], al[4];                                                                \
        _Pragma("unroll")                                                                   \
        for (int rf = 0; rf < 4; ++rf) {                                                    \
            int u = (lg * 64 + rf * 16 + lr) ^ (lg << 1);                                   \
            ah[rf] = *(const short8*)&Xh[P][u * 8];                                         \
            al[rf] = *(const short8*)&Xl[P][u * 8];                                         \
        }                                                                                   \
        /* cvt X(s+1) regs -> LDS[P^1] (safe: step s-1 readers done at last barrier) */     \
        if (s_ + 1 < NSTEP)                                                                 \
            cvt_store(nxa[(P) ^ 1], nxb[(P) ^ 1], &Xh[(P) ^ 1][xu * 8], &Xl[(P) ^ 1][xu * 8]); \
        /* issue X(s+2) -> nx[P] */                                                         \
        if (s_ + 2 < NSTEP) {                                                               \
            nxa[P] = __builtin_nontemporal_load((const f32x4*)(xp_base + (s_ + 2) * BK));   \
            nxb[P] = __builtin_nontemporal_load((const f32x4*)(xp_base + (s_ + 2) * BK + 4)); \
        }                                                                                   \
        /* issue W(s+1) -> w[P^1] */                                                        \
        if (s_ + 1 < NSTEP) {                                                               \
            const unsigned short* wsrc = wlane + (size_t)(s_ + 1) * 16384;                  \
            _Pragma("unroll")                                                               \
            for (int cf = 0; cf < 4; ++cf) {                                                \
                wh[(P) ^ 1][cf] = *(const short8*)(wsrc + cf * 128);                        \
                wl[(P) ^ 1][cf] = *(const short8*)(wsrc + cf * 128 + 8192);                 \
            }                                                                               \
        }                                                                                   \
        /* MFMA with W(s) regs */                                                           \
        _Pragma("unroll")                                                                   \
        for (int cf = 0; cf < 4; ++cf) {                                                    \
            _Pragma("unroll")                                                               \
            for (int rf = 0; rf < 4; ++rf) {                                                \
                acc[rf][cf] = __builtin_amdgcn_mfma_f32_16x16x32_bf16(al[rf], wh[P][cf], acc[rf][cf], 0, 0, 0); \
                acc[rf][cf] = __builtin_amdgcn_mfma_f32_16x16x32_bf16(ah[rf], wl[P][cf], acc[rf][cf], 0, 0, 0); \
                acc[rf][cf] = __builtin_amdgcn_mfma_f32_16x16x32_bf16(ah[rf], wh[P][cf], acc[rf][cf], 0, 0, 0); \
            }                                                                               \
        }                                                                                   \
        __syncthreads();                                                                    \
    }

#pragma unroll 1
    for (int s2 = 0; s2 < NSTEP / 2; ++s2) {
        HALF(0, 2 * s2);
        HALF(1, 2 * s2 + 1);
    }
#undef HALF

    // --- epilogue: per-row top-2 (C/D layout: col=lane&15, row=(lane>>4)*4+reg) ---
    float c2v[4];
#pragma unroll
    for (int cf = 0; cf < 4; ++cf) c2v[cf] = c2[wv * 64 + cf * 16 + lr];

#pragma unroll
    for (int rf = 0; rf < 4; ++rf) {
#pragma unroll
        for (int reg = 0; reg < 4; ++reg) {
            float v1 = 3.4e38f, v2 = 3.4e38f;
            int   c1 = 1 << 20;
#pragma unroll
            for (int cf = 0; cf < 4; ++cf) {
                float sc = acc[rf][cf][reg] + c2v[cf];
                int col = wv * 64 + cf * 16 + lr;
                if (sc < v1 || (sc == v1 && col < c1)) { v2 = v1; v1 = sc; c1 = col; }
                else if (sc < v2) v2 = sc;
            }
#pragma unroll
            for (int off = 1; off < 16; off <<= 1) {
                float ov1 = __shfl_xor(v1, off);
                float ov2 = __shfl_xor(v2, off);
                int   oc1 = __shfl_xor(c1, off);
                if (ov1 < v1 || (ov1 == v1 && oc1 < c1)) { v2 = fminf(v1, ov2); v1 = ov1; c1 = oc1; }
                else v2 = fminf(v2, ov1);
            }
            if (lr == 0) {
                int r = rf * 16 + lg * 4 + reg;
                Rv1[r * 4 + wv] = v1; Ri1[r * 4 + wv] = c1; Rv2[r * 4 + wv] = v2;
            }
        }
    }
    __syncthreads();

    if (t < BM) {
        float v1 = Rv1[t * 4], v2 = Rv2[t * 4];
        int   c1 = Ri1[t * 4];
#pragma unroll
        for (int g = 1; g < 4; ++g) {
            float bv = Rv1[t * 4 + g], bs = Rv2[t * 4 + g];
            int   bc = Ri1[t * 4 + g];
            if (bv < v1) { v2 = fminf(v1, bs); v1 = bv; c1 = bc; }
            else         { v2 = fminf(v2, bv); }
        }
        rowIdx[t] = c1;
        if (v2 - v1 < MARGIN_TH) {
            int pos = atomicAdd(counter, 1);
            list[pos] = row0 + t;
        }
    }
    __syncthreads();

    // --- gather + write: 64 rows x 512 f32, coalesced f32x4, nontemporal ---
#pragma unroll
    for (int m = 0; m < 32; ++m) {
        int lin = m * 256 + t;            // 0..8191
        int r   = lin >> 7;               // 0..63
        int c4  = (lin & 127) * 4;
        f32x4 v = *(const f32x4*)(Tdec + (size_t)rowIdx[r] * DD + c4);
        __builtin_nontemporal_store(v, (f32x4*)(out + (size_t)(row0 + r) * DD + c4));
    }
}

// ---------------- refine: fp64-exact re-decision for near-tie rows ----------------------
__global__ __launch_bounds__(256) void refine_kernel(const float* __restrict__ X,
                                                     const float* __restrict__ enc_w,
                                                     const float* __restrict__ enc_b,
                                                     const float* __restrict__ cb,
                                                     const float* __restrict__ Tdec,
                                                     float* __restrict__ out,
                                                     const int* __restrict__ counter,
                                                     const int* __restrict__ list) {
    int cnt = *counter;
    __shared__ double r0[DD];
    __shared__ double sv[256];
    __shared__ int    si[256];
    for (int it = blockIdx.x; it < cnt; it += gridDim.x) {
        int n = list[it];
        const float* xr = X + (size_t)n * DIN;
        for (int d = threadIdx.x; d < DD; d += 256) {
            double a0 = 0, a1 = 0, a2 = 0, a3 = 0;
            for (int j = 0; j < DIN; j += 4) {
                a0 += (double)xr[j]     * (double)enc_w[(size_t)(j)     * DD + d];
                a1 += (double)xr[j + 1] * (double)enc_w[(size_t)(j + 1) * DD + d];
                a2 += (double)xr[j + 2] * (double)enc_w[(size_t)(j + 2) * DD + d];
                a3 += (double)xr[j + 3] * (double)enc_w[(size_t)(j + 3) * DD + d];
            }
            r0[d] = (double)enc_b[d] + a0 + a1 + a2 + a3;
        }
        __syncthreads();
        int k = threadIdx.x;
        const float* ck = cb + (size_t)k * DD;
        double d0 = 0, d1 = 0, n0 = 0, n1 = 0;
        for (int d = 0; d < DD; d += 2) {
            double c0 = ck[d], c1 = ck[d + 1];
            d0 += r0[d] * c0;     n0 += c0 * c0;
            d1 += r0[d + 1] * c1; n1 += c1 * c1;
        }
        sv[k] = -2.0 * (d0 + d1) + (n0 + n1); si[k] = k;
        __syncthreads();
        for (int off = 128; off; off >>= 1) {
            if (k < off) {
                double a = sv[k], b = sv[k + off];
                if (b < a || (b == a && si[k + off] < si[k])) { sv[k] = b; si[k] = si[k + off]; }
            }
            __syncthreads();
        }
        int best = si[0];
        for (int c = threadIdx.x; c < DD; c += 256)
            out[(size_t)n * DD + c] = Tdec[(size_t)best * DD + c];
        __syncthreads();
    }
}

extern "C" void kernel_launch(void* const* d_in, const int* in_sizes, int n_in,
                              void* d_out, int out_size, void* d_ws, size_t ws_size,
                              hipStream_t stream) {
    const float* X     = (const float*)d_in[0];
    const float* enc_w = (const float*)d_in[1];
    const float* enc_b = (const float*)d_in[2];
    const float* cb    = (const float*)d_in[3];
    const float* dec_w = (const float*)d_in[4];
    const float* dec_b = (const float*)d_in[5];
    float* out = (float*)d_out;

    char* ws = (char*)d_ws;
    unsigned short* Wp = (unsigned short*)(ws + 0);          // 24*2048*8*2B = 786432
    float* c2      = (float*)(ws + 786432);                  // 1024
    float* Tdec    = (float*)(ws + 787456);                  // 524288
    int*   counter = (int*)  (ws + 1311744);                 // 4 (+pad)
    int*   list    = (int*)  (ws + 1311776);                 // near-tie rows

    hipLaunchKernelGGL(pre_kernel,   dim3(1024),       dim3(256), 0, stream,
                       enc_w, enc_b, cb, dec_w, dec_b, Wp, c2, Tdec, counter);
    hipLaunchKernelGGL(bulk_kernel,  dim3(NROWS / BM), dim3(256), 0, stream,
                       X, Wp, c2, Tdec, out, counter, list);
    hipLaunchKernelGGL(refine_kernel, dim3(1024),      dim3(256), 0, stream,
                       X, enc_w, enc_b, cb, Tdec, out, counter, list);
}